// Round 2
// baseline (685.473 us; speedup 1.0000x reference)
//
#include <hip/hip_runtime.h>

#define BB   16
#define SS   512
#define DD   1024
#define HH   16
#define DKK  64
#define DFFN 4096
#define LN_EPS 1e-6f

typedef __attribute__((ext_vector_type(8))) __bf16 bf16x8;
typedef __attribute__((ext_vector_type(4))) float f32x4;
typedef __attribute__((ext_vector_type(8))) unsigned short ushort8;
typedef __attribute__((ext_vector_type(4))) unsigned short ushort4_t;

#define AS1 __attribute__((address_space(1)))
#define AS3 __attribute__((address_space(3)))

__device__ __forceinline__ unsigned short f2bf(float f) {
  unsigned int u = __float_as_uint(f);
  u += 0x7FFFu + ((u >> 16) & 1u);   // round-nearest-even
  return (unsigned short)(u >> 16);
}
__device__ __forceinline__ float bf2f(unsigned short u) {
  return __uint_as_float(((unsigned int)u) << 16);
}

__device__ __forceinline__ float gelu_f(float x) {
  float x3 = x * x * x;
  return 0.5f * x * (1.0f + tanhf(0.7978845608028654f * (x + 0.044715f * x3)));
}

// ---------------- LayerNorm: fp32 in -> bf16 out (strided out)
__global__ __launch_bounds__(256) void ln_kernel(const float* __restrict__ x,
                                                 const float* __restrict__ g,
                                                 const float* __restrict__ b,
                                                 unsigned short* __restrict__ out, int ldo) {
  const int row = blockIdx.x;
  const int tid = threadIdx.x;
  const float* xr = x + (size_t)row * DD;
  float4 v = *(const float4*)(xr + tid * 4);
  float s = v.x + v.y + v.z + v.w;
#pragma unroll
  for (int off = 1; off < 64; off <<= 1) s += __shfl_xor(s, off);
  __shared__ float red[8];
  const int wid = tid >> 6, l = tid & 63;
  if (l == 0) red[wid] = s;
  __syncthreads();
  const float mean = (red[0] + red[1] + red[2] + red[3]) * (1.0f / DD);
  float4 d;
  d.x = v.x - mean; d.y = v.y - mean; d.z = v.z - mean; d.w = v.w - mean;
  float ss = d.x * d.x + d.y * d.y + d.z * d.z + d.w * d.w;
#pragma unroll
  for (int off = 1; off < 64; off <<= 1) ss += __shfl_xor(ss, off);
  if (l == 0) red[4 + wid] = ss;
  __syncthreads();
  const float var = (red[4] + red[5] + red[6] + red[7]) * (1.0f / (DD - 1));
  const float scale = 1.0f / (sqrtf(var) + LN_EPS);
  float4 gv = *(const float4*)(g + tid * 4);
  float4 bv = *(const float4*)(b + tid * 4);
  ushort4_t o;
  o[0] = f2bf(gv.x * d.x * scale + bv.x);
  o[1] = f2bf(gv.y * d.y * scale + bv.y);
  o[2] = f2bf(gv.z * d.z * scale + bv.z);
  o[3] = f2bf(gv.w * d.w * scale + bv.w);
  *(ushort4_t*)(out + (size_t)row * ldo + tid * 4) = o;
}

// ---------------- fp32 -> bf16, strided rows of DD elems
__global__ __launch_bounds__(256) void cvt_bf16(const float* __restrict__ in,
                                                unsigned short* __restrict__ out, int ldo) {
  const int i = blockIdx.x * 256 + threadIdx.x;  // i over MT*DD/8
  const int row = i >> 7;
  const int c0 = (i & 127) * 8;
  const float4* p = (const float4*)(in + (size_t)row * DD + c0);
  float4 a = p[0], b = p[1];
  ushort8 o;
  o[0] = f2bf(a.x); o[1] = f2bf(a.y); o[2] = f2bf(a.z); o[3] = f2bf(a.w);
  o[4] = f2bf(b.x); o[5] = f2bf(b.y); o[6] = f2bf(b.z); o[7] = f2bf(b.w);
  *(ushort8*)(out + (size_t)row * ldo + c0) = o;
}

// ---------------- W[K][N] fp32 -> WT[N][K] bf16 (strided out rows)
__global__ __launch_bounds__(256) void transpose_cvt(const float* __restrict__ W,
                                                     unsigned short* __restrict__ WT,
                                                     int N, int ldo) {
  __shared__ float tile[32][33];
  const int tx = threadIdx.x & 31, ty = threadIdx.x >> 5;  // ty 0..7
  const int n0 = blockIdx.x * 32, k0 = blockIdx.y * 32;
#pragma unroll
  for (int i = 0; i < 32; i += 8)
    tile[ty + i][tx] = W[(size_t)(k0 + ty + i) * N + n0 + tx];
  __syncthreads();
#pragma unroll
  for (int i = 0; i < 32; i += 8)
    WT[(size_t)(n0 + ty + i) * ldo + k0 + tx] = f2bf(tile[tx][ty + i]);
}

// ---------------- bias prep: qvb = concat(bq,bv) ; kcb = bk+bt
__global__ __launch_bounds__(256) void bias_prep(const float* __restrict__ bq,
                                                 const float* __restrict__ bv,
                                                 const float* __restrict__ bk,
                                                 const float* __restrict__ bt,
                                                 float* __restrict__ qvb,
                                                 float* __restrict__ kcb) {
  const int i = blockIdx.x * 256 + threadIdx.x;
  if (i < 2048) qvb[i] = (i < 1024) ? bq[i] : bv[i - 1024];
  else kcb[i - 2048] = bk[i - 2048] + bt[i - 2048];
}

// ---------------- mask int32 -> bitmask u64 (1 bit per key)
__global__ __launch_bounds__(256) void mask_pack(const int* __restrict__ mask,
                                                 unsigned long long* __restrict__ bits) {
  const int gid = blockIdx.x * 256 + threadIdx.x;
  const int m = mask[gid];
  const unsigned long long b = __ballot(m != 0);
  if ((threadIdx.x & 63) == 0) bits[gid >> 6] = b;
}

// ---------------- sigmoid(ml) -> bf16
__global__ __launch_bounds__(256) void sig_cvt(const float* __restrict__ ml,
                                               unsigned short* __restrict__ sg) {
  const int i = blockIdx.x * 256 + threadIdx.x;  // over S*S/8
  const float4* p = (const float4*)(ml + (size_t)i * 8);
  float4 a = p[0], b = p[1];
  ushort8 o;
  o[0] = f2bf(1.0f / (1.0f + __expf(-a.x)));
  o[1] = f2bf(1.0f / (1.0f + __expf(-a.y)));
  o[2] = f2bf(1.0f / (1.0f + __expf(-a.z)));
  o[3] = f2bf(1.0f / (1.0f + __expf(-a.w)));
  o[4] = f2bf(1.0f / (1.0f + __expf(-b.x)));
  o[5] = f2bf(1.0f / (1.0f + __expf(-b.y)));
  o[6] = f2bf(1.0f / (1.0f + __expf(-b.z)));
  o[7] = f2bf(1.0f / (1.0f + __expf(-b.w)));
  *(ushort8*)(sg + (size_t)i * 8) = o;
}

// ---------------- GEMM: C[M][N] = A[M][K](bf16,lda) @ BT[N][K](bf16)^T + bias
// EPI 0: -> bf16 ; EPI 1: +resid -> f32 ; EPI 2: gelu -> bf16
#define GBM 128
#define GBN 128
#define GBK 64

template <int EPI>
__global__ __launch_bounds__(256) void gemm_bt(const unsigned short* __restrict__ A, int lda,
                                               const unsigned short* __restrict__ BT,
                                               const float* __restrict__ bias,
                                               const float* __restrict__ resid,
                                               void* __restrict__ Cout,
                                               int M, int N, int K) {
  __shared__ __align__(16) unsigned short smA[GBM * GBK];
  __shared__ __align__(16) unsigned short smB[GBN * GBK];
  const int tid = threadIdx.x;
  const int nb = N / GBN;
  // bijective XCD swizzle (all grids here are %8==0)
  const int nwg = gridDim.x;
  int bid = blockIdx.x;
  if ((nwg & 7) == 0) bid = (bid & 7) * (nwg >> 3) + (bid >> 3);
  const int mb = bid / nb;
  const int nbk = bid % nb;
  const int wid = tid >> 6, l = tid & 63;
  const int wr = wid >> 1, wc = wid & 1;
  const int lr = l & 15, lg = l >> 4;
  const int srow = tid >> 3;       // 0..31
  const int scol = (tid & 7) * 8;

  f32x4 acc[4][4] = {};
  const unsigned short* Abase = A + (size_t)mb * GBM * lda + (size_t)srow * lda + scol;
  const unsigned short* Bbase = BT + (size_t)nbk * GBN * K + (size_t)srow * K + scol;

  for (int kt = 0; kt < K; kt += GBK) {
#pragma unroll
    for (int c = 0; c < 4; ++c)
      __builtin_amdgcn_global_load_lds((const AS1 void*)(Abase + kt + (size_t)c * 32 * lda),
                                       (AS3 void*)(smA + c * 2048 + wid * 512), 16, 0, 0);
#pragma unroll
    for (int c = 0; c < 4; ++c)
      __builtin_amdgcn_global_load_lds((const AS1 void*)(Bbase + kt + (size_t)c * 32 * K),
                                       (AS3 void*)(smB + c * 2048 + wid * 512), 16, 0, 0);
    __syncthreads();
#pragma unroll
    for (int ks = 0; ks < 2; ++ks) {
      bf16x8 af[4], bfr[4];
#pragma unroll
      for (int mi = 0; mi < 4; ++mi)
        af[mi] = *(const bf16x8*)(smA + (wr * 64 + mi * 16 + lr) * GBK + ks * 32 + lg * 8);
#pragma unroll
      for (int ni = 0; ni < 4; ++ni)
        bfr[ni] = *(const bf16x8*)(smB + (wc * 64 + ni * 16 + lr) * GBK + ks * 32 + lg * 8);
#pragma unroll
      for (int mi = 0; mi < 4; ++mi)
#pragma unroll
        for (int ni = 0; ni < 4; ++ni)
          acc[mi][ni] = __builtin_amdgcn_mfma_f32_16x16x32_bf16(af[mi], bfr[ni], acc[mi][ni], 0, 0, 0);
    }
    __syncthreads();
  }

  const int colb = nbk * GBN + wc * 64;
  const int rowb = mb * GBM + wr * 64;
#pragma unroll
  for (int ni = 0; ni < 4; ++ni) {
    const int col = colb + ni * 16 + lr;
    const float bv = bias[col];
#pragma unroll
    for (int mi = 0; mi < 4; ++mi) {
#pragma unroll
      for (int j = 0; j < 4; ++j) {
        const int row = rowb + mi * 16 + lg * 4 + j;
        float vv = acc[mi][ni][j] + bv;
        if (EPI == 2) vv = gelu_f(vv);
        const size_t o = (size_t)row * N + col;
        if (EPI == 1) {
          ((float*)Cout)[o] = vv + resid[o];
        } else {
          ((unsigned short*)Cout)[o] = f2bf(vv);
        }
      }
    }
  }
}

// ---------------- Fused attention v2: one block per (b,h), 8 waves.
// kc = k1+k2 precombined. V transposed+swizzled in LDS once; kc/V fragments
// hoisted to registers; 16 q-tiles of 32 rows; mask from packed bits;
// sigmoid(ml) precomputed bf16.
__global__ __launch_bounds__(512) void attn2(const unsigned short* __restrict__ qv,
                                             const unsigned short* __restrict__ kcb,
                                             const unsigned long long* __restrict__ mbits,
                                             const unsigned short* __restrict__ sg,
                                             unsigned short* __restrict__ ctx) {
  __shared__ __align__(16) unsigned short Vt[64 * 512];  // [dk][key] swizzled
  __shared__ __align__(16) unsigned short Ps[32 * 512];  // [row][key] swizzled
  __shared__ float redm[32 * 8];
  __shared__ float reds[32 * 8];

  const int tid = threadIdx.x;
  const int h = blockIdx.x & (HH - 1);
  const int b = blockIdx.x >> 4;
  const int wid = tid >> 6, l = tid & 63;
  const int lr = l & 15, lg = l >> 4;

  const unsigned short* qg = qv + (size_t)b * SS * 2048 + h * DKK;
  const unsigned short* vg = qg + 1024;
  const unsigned short* kg = kcb + (size_t)b * SS * DD + h * DKK;
  unsigned short* cg = ctx + (size_t)b * SS * DD + h * DKK;

  // stage V transposed + swizzled (element ^= (dk&7)<<3 on key index)
#pragma unroll
  for (int i = 0; i < 8; ++i) {
    const int idx = i * 512 + tid;
    const int key = idx >> 3;
    const int d0 = (idx & 7) * 8;
    ushort8 vv = *(const ushort8*)(vg + (size_t)key * 2048 + d0);
#pragma unroll
    for (int j = 0; j < 8; ++j) {
      const int dk = d0 + j;
      Vt[dk * 512 + (key ^ ((dk & 7) << 3))] = vv[j];
    }
  }

  // kc B-fragments, direct global->reg, one-time. wave covers keys wid*64..+63
  bf16x8 kb[4][2];
#pragma unroll
  for (int ni = 0; ni < 4; ++ni)
#pragma unroll
    for (int ks = 0; ks < 2; ++ks)
      kb[ni][ks] = *(const bf16x8*)(kg + (size_t)(wid * 64 + ni * 16 + lr) * DD + ks * 32 + lg * 8);

  __syncthreads();

  // hoist Vt fragments for this wave's PV output tile
  const int mo = wid >> 2, no = wid & 3;  // output rows mo*16, dk cols no*16
  bf16x8 vb[16];
  {
    const int dk = no * 16 + lr;
    const int sw = (dk & 7) << 3;
#pragma unroll
    for (int kk = 0; kk < 16; ++kk)
      vb[kk] = *(const bf16x8*)(Vt + dk * 512 + ((kk * 32 + lg * 8) ^ sw));
  }

  for (int qt = 0; qt < 16; ++qt) {
    const int q0 = qt * 32;
    bf16x8 af[2][2];
#pragma unroll
    for (int mi = 0; mi < 2; ++mi)
#pragma unroll
      for (int ks = 0; ks < 2; ++ks)
        af[mi][ks] = *(const bf16x8*)(qg + (size_t)(q0 + mi * 16 + lr) * 2048 + ks * 32 + lg * 8);

    f32x4 sc[2][4] = {};
#pragma unroll
    for (int ks = 0; ks < 2; ++ks)
#pragma unroll
      for (int mi = 0; mi < 2; ++mi)
#pragma unroll
        for (int ni = 0; ni < 4; ++ni)
          sc[mi][ni] = __builtin_amdgcn_mfma_f32_16x16x32_bf16(af[mi][ks], kb[ni][ks], sc[mi][ni], 0, 0, 0);

    // scale + mask + per-wave row max
    float mx[2][4];
#pragma unroll
    for (int mi = 0; mi < 2; ++mi)
#pragma unroll
      for (int j = 0; j < 4; ++j) {
        mx[mi][j] = -3e38f;
        const int rowg = q0 + mi * 16 + lg * 4 + j;
        const unsigned long long mw = mbits[((size_t)b * SS + rowg) * 8 + wid];
#pragma unroll
        for (int ni = 0; ni < 4; ++ni) {
          float s = sc[mi][ni][j] * 0.125f;
          s = ((mw >> (ni * 16 + lr)) & 1ull) ? s : -1e9f;
          sc[mi][ni][j] = s;
          mx[mi][j] = fmaxf(mx[mi][j], s);
        }
      }
#pragma unroll
    for (int mi = 0; mi < 2; ++mi)
#pragma unroll
      for (int j = 0; j < 4; ++j) {
        float m = mx[mi][j];
        m = fmaxf(m, __shfl_xor(m, 1));
        m = fmaxf(m, __shfl_xor(m, 2));
        m = fmaxf(m, __shfl_xor(m, 4));
        m = fmaxf(m, __shfl_xor(m, 8));
        if (lr == 0) redm[(mi * 16 + lg * 4 + j) * 8 + wid] = m;
      }
    __syncthreads();

    float rsum[2][4];
#pragma unroll
    for (int mi = 0; mi < 2; ++mi)
#pragma unroll
      for (int j = 0; j < 4; ++j) {
        const int rl = mi * 16 + lg * 4 + j;
        const float* r = redm + rl * 8;
        float rm = fmaxf(fmaxf(fmaxf(r[0], r[1]), fmaxf(r[2], r[3])),
                         fmaxf(fmaxf(r[4], r[5]), fmaxf(r[6], r[7])));
        float s = 0.f;
#pragma unroll
        for (int ni = 0; ni < 4; ++ni) {
          const float p = __expf(sc[mi][ni][j] - rm);
          sc[mi][ni][j] = p;
          s += p;
        }
        s += __shfl_xor(s, 1);
        s += __shfl_xor(s, 2);
        s += __shfl_xor(s, 4);
        s += __shfl_xor(s, 8);
        if (lr == 0) reds[rl * 8 + wid] = s;
        rsum[mi][j] = 0.f;
      }
    __syncthreads();

    // normalize * sigmoid, write P (swizzled)
#pragma unroll
    for (int mi = 0; mi < 2; ++mi)
#pragma unroll
      for (int j = 0; j < 4; ++j) {
        const int rl = mi * 16 + lg * 4 + j;
        const float* r = reds + rl * 8;
        const float rinv = 1.0f / (((r[0] + r[1]) + (r[2] + r[3])) + ((r[4] + r[5]) + (r[6] + r[7])));
        rsum[mi][j] = rinv;
        const int rowg = q0 + rl;
        const int sw = (rl & 7) << 3;
#pragma unroll
        for (int ni = 0; ni < 4; ++ni) {
          const int col = wid * 64 + ni * 16 + lr;
          const float sig = bf2f(sg[(size_t)rowg * SS + col]);
          Ps[rl * 512 + (col ^ sw)] = f2bf(sc[mi][ni][j] * rinv * sig);
        }
      }
    __syncthreads();

    // PV: each wave one 16x16 output tile, contract 512 keys
    f32x4 acc = {};
    {
      const int row = mo * 16 + lr;
      const int sw = (row & 7) << 3;
#pragma unroll
      for (int kk = 0; kk < 16; ++kk) {
        bf16x8 pa = *(const bf16x8*)(Ps + row * 512 + ((kk * 32 + lg * 8) ^ sw));
        acc = __builtin_amdgcn_mfma_f32_16x16x32_bf16(pa, vb[kk], acc, 0, 0, 0);
      }
    }
#pragma unroll
    for (int j = 0; j < 4; ++j)
      cg[(size_t)(q0 + mo * 16 + lg * 4 + j) * DD + no * 16 + lr] = f2bf(acc[j]);
    __syncthreads();
  }
}

// ----------------------------------------------------------------------------
extern "C" void kernel_launch(void* const* d_in, const int* in_sizes, int n_in,
                              void* d_out, int out_size, void* d_ws, size_t ws_size,
                              hipStream_t stream) {
  (void)in_sizes; (void)n_in; (void)out_size; (void)ws_size;
  const float* x    = (const float*)d_in[0];
  const float* timep= (const float*)d_in[1];
  const float* Wq = (const float*)d_in[2];  const float* bq = (const float*)d_in[3];
  const float* Wk = (const float*)d_in[4];  const float* bk = (const float*)d_in[5];
  const float* Wt = (const float*)d_in[6];  const float* bt = (const float*)d_in[7];
  const float* Wv = (const float*)d_in[8];  const float* bv = (const float*)d_in[9];
  const float* Wo = (const float*)d_in[10]; const float* bo = (const float*)d_in[11];
  const float* W1 = (const float*)d_in[12]; const float* b1 = (const float*)d_in[13];
  const float* W2 = (const float*)d_in[14]; const float* b2 = (const float*)d_in[15];
  const float* ln1g = (const float*)d_in[16]; const float* ln1b = (const float*)d_in[17];
  const float* ln2g = (const float*)d_in[18]; const float* ln2b = (const float*)d_in[19];
  const float* ml   = (const float*)d_in[20];
  const int*   mask = (const int*)d_in[21];
  float* out = (float*)d_out;

  char* w = (char*)d_ws;
  auto alloc = [&](size_t sz) { char* p = w; w += (sz + 255) & ~(size_t)255; return p; };
  const int MT = BB * SS;  // 8192 rows

  unsigned short* WqvT = (unsigned short*)alloc((size_t)2048 * 1024 * 2);  // [2048][1024]
  unsigned short* WkcT = (unsigned short*)alloc((size_t)1024 * 2048 * 2);  // [1024][2048]
  unsigned short* WoT  = (unsigned short*)alloc((size_t)DD * DD * 2);
  unsigned short* W1T  = (unsigned short*)alloc((size_t)DD * DFFN * 2);    // [DFFN][DD]
  unsigned short* W2T  = (unsigned short*)alloc((size_t)DFFN * DD * 2);    // [DD][DFFN]
  float* qvb = (float*)alloc(2048 * 4);
  float* kcbias = (float*)alloc(1024 * 4);
  unsigned long long* mbits = (unsigned long long*)alloc((size_t)BB * SS * 8 * 8);
  unsigned short* sg  = (unsigned short*)alloc((size_t)SS * SS * 2);
  unsigned short* xt2 = (unsigned short*)alloc((size_t)MT * 2048 * 2);  // [xn | time]
  unsigned short* qvo = (unsigned short*)alloc((size_t)MT * 2048 * 2);  // [q | v]
  unsigned short* kcb = (unsigned short*)alloc((size_t)MT * DD * 2);    // k1+k2
  float*          x2  = (float*)alloc((size_t)MT * DD * 4);
  unsigned short* hb  = (unsigned short*)alloc((size_t)MT * DFFN * 2);
  unsigned short* ctx = xt2;          // xt2 dead after kc GEMM
  unsigned short* xn2 = xt2;          // ctx dead after Wo GEMM

  // weight prep
  transpose_cvt<<<dim3(32, 32), 256, 0, stream>>>(Wq, WqvT, 1024, 1024);
  transpose_cvt<<<dim3(32, 32), 256, 0, stream>>>(Wv, WqvT + (size_t)1024 * 1024, 1024, 1024);
  transpose_cvt<<<dim3(32, 32), 256, 0, stream>>>(Wk, WkcT, 1024, 2048);
  transpose_cvt<<<dim3(32, 32), 256, 0, stream>>>(Wt, WkcT + 1024, 1024, 2048);
  transpose_cvt<<<dim3(32, 32), 256, 0, stream>>>(Wo, WoT, 1024, 1024);
  transpose_cvt<<<dim3(128, 32), 256, 0, stream>>>(W1, W1T, 4096, 1024);
  transpose_cvt<<<dim3(32, 128), 256, 0, stream>>>(W2, W2T, 1024, 4096);
  bias_prep<<<dim3(12), 256, 0, stream>>>(bq, bv, bk, bt, qvb, kcbias);
  mask_pack<<<dim3(BB * SS * SS / 256), 256, 0, stream>>>(mask, mbits);
  sig_cvt<<<dim3(SS * SS / 8 / 256), 256, 0, stream>>>(ml, sg);

  // xt2 = [ln1(x) | bf16(time)]
  ln_kernel<<<dim3(MT), 256, 0, stream>>>(x, ln1g, ln1b, xt2, 2048);
  cvt_bf16<<<dim3(MT * DD / 8 / 256), 256, 0, stream>>>(timep, xt2 + 1024, 2048);

  // projections: qv (N=2048,K=1024) ; kc (N=1024,K=2048)
  gemm_bt<0><<<dim3((MT / GBM) * (2048 / GBN)), 256, 0, stream>>>(xt2, 2048, WqvT, qvb, nullptr, (void*)qvo, MT, 2048, 1024);
  gemm_bt<0><<<dim3((MT / GBM) * (1024 / GBN)), 256, 0, stream>>>(xt2, 2048, WkcT, kcbias, nullptr, (void*)kcb, MT, 1024, 2048);

  attn2<<<dim3(BB * HH), 512, 0, stream>>>(qvo, kcb, mbits, sg, ctx);

  gemm_bt<1><<<dim3((MT / GBM) * (1024 / GBN)), 256, 0, stream>>>(ctx, 1024, WoT, bo, x, (void*)x2, MT, 1024, 1024);
  ln_kernel<<<dim3(MT), 256, 0, stream>>>(x2, ln2g, ln2b, xn2, 1024);
  gemm_bt<2><<<dim3((MT / GBM) * (DFFN / GBN)), 256, 0, stream>>>(xn2, 1024, W1T, b1, nullptr, (void*)hb, MT, DFFN, 1024);
  gemm_bt<1><<<dim3((MT / GBM) * (1024 / GBN)), 256, 0, stream>>>(hb, 4096, W2T, b2, x2, (void*)out, MT, 1024, DFFN);
}